// Round 6
// baseline (955.080 us; speedup 1.0000x reference)
//
#include <hip/hip_runtime.h>

#define N_NODES 50000
#define N_EDGES 1600000
#define D_FEAT 512
#define FILTERS 256
#define NUM_CLASSES 16

typedef __bf16 bf16x8 __attribute__((ext_vector_type(8)));
typedef float f32x4 __attribute__((ext_vector_type(4)));
typedef _Float16 half8 __attribute__((ext_vector_type(8)));

#define GLOAD_LDS16(g, l)                                                  \
  __builtin_amdgcn_global_load_lds(                                        \
      (const __attribute__((address_space(1))) unsigned int*)(g),          \
      (__attribute__((address_space(3))) unsigned int*)(l), 16, 0, 0)

// ---------------------------------------------------------------------------
// Split W1 [512,256] fp32 -> W1^T hi/lo bf16 [256,512]
// ---------------------------------------------------------------------------
__global__ __launch_bounds__(256) void split_w1_kernel(
    const float* __restrict__ W1, __bf16* __restrict__ Wth,
    __bf16* __restrict__ Wtl) {
  const int idx = blockIdx.x * 256 + threadIdx.x;
  const int k = idx >> 8;
  const int n = idx & 255;
  const float v = W1[idx];
  const __bf16 h = (__bf16)v;
  const __bf16 l = (__bf16)(v - (float)h);
  Wth[n * D_FEAT + k] = h;
  Wtl[n * D_FEAT + k] = l;
}

// ---------------------------------------------------------------------------
// GEMM1 via MFMA bf16x3: XW1 = X @ W1, fp32-accurate, output stored fp16.
// ---------------------------------------------------------------------------
__global__ __launch_bounds__(256) void gemm1_mfma_kernel(
    const float* __restrict__ A, const __bf16* __restrict__ Bh,
    const __bf16* __restrict__ Bl, _Float16* __restrict__ C) {
  const int K = D_FEAT;
  __shared__ __bf16 sAh[128 * 32];
  __shared__ __bf16 sAl[128 * 32];
  __shared__ __bf16 sBh[128 * 32];
  __shared__ __bf16 sBl[128 * 32];

  const int tid = threadIdx.x;
  const int wave = tid >> 6;
  const int lane = tid & 63;
  const int wm = (wave >> 1) * 64;
  const int wn = (wave & 1) * 64;
  const int m0 = blockIdx.x * 128;
  const int n0 = blockIdx.y * 128;

  const int arow = tid >> 1;
  const int aks = (tid & 1) * 16;
  int am = m0 + arow;
  if (am >= N_NODES) am = N_NODES - 1;
  const float* aptr = A + (size_t)am * K + aks;

  const int lr = lane >> 2;
  const int lc = (lane & 3) * 8;
  const int fm = lane & 15;
  const int fq = lane >> 4;

  f32x4 acc[4][4] = {};

  for (int k0 = 0; k0 < K; k0 += 32) {
    const float4* ap = (const float4*)(aptr + k0);
    const float4 a0 = ap[0], a1 = ap[1], a2 = ap[2], a3 = ap[3];

    __syncthreads();

#pragma unroll
    for (int i = 0; i < 2; ++i) {
      const int row = wave * 32 + i * 16;
      GLOAD_LDS16(Bh + (size_t)(n0 + row + lr) * K + k0 + lc, sBh + row * 32);
      GLOAD_LDS16(Bl + (size_t)(n0 + row + lr) * K + k0 + lc, sBl + row * 32);
    }

    float va[16] = {a0.x, a0.y, a0.z, a0.w, a1.x, a1.y, a1.z, a1.w,
                    a2.x, a2.y, a2.z, a2.w, a3.x, a3.y, a3.z, a3.w};
    __bf16 hh[16], ll[16];
#pragma unroll
    for (int i = 0; i < 16; ++i) {
      const __bf16 h = (__bf16)va[i];
      hh[i] = h;
      ll[i] = (__bf16)(va[i] - (float)h);
    }
    *(bf16x8*)(sAh + arow * 32 + aks) = *(bf16x8*)&hh[0];
    *(bf16x8*)(sAh + arow * 32 + aks + 8) = *(bf16x8*)&hh[8];
    *(bf16x8*)(sAl + arow * 32 + aks) = *(bf16x8*)&ll[0];
    *(bf16x8*)(sAl + arow * 32 + aks + 8) = *(bf16x8*)&ll[8];

    __syncthreads();

    bf16x8 fah[4], fal[4], fbh[4], fbl[4];
#pragma unroll
    for (int t = 0; t < 4; ++t) {
      const int moff = (wm + t * 16 + fm) * 32 + fq * 8;
      fah[t] = *(const bf16x8*)(sAh + moff);
      fal[t] = *(const bf16x8*)(sAl + moff);
      const int noff = (wn + t * 16 + fm) * 32 + fq * 8;
      fbh[t] = *(const bf16x8*)(sBh + noff);
      fbl[t] = *(const bf16x8*)(sBl + noff);
    }
#pragma unroll
    for (int i = 0; i < 4; ++i)
#pragma unroll
      for (int j = 0; j < 4; ++j)
        acc[i][j] = __builtin_amdgcn_mfma_f32_16x16x32_bf16(fah[i], fbh[j],
                                                            acc[i][j], 0, 0, 0);
#pragma unroll
    for (int i = 0; i < 4; ++i)
#pragma unroll
      for (int j = 0; j < 4; ++j)
        acc[i][j] = __builtin_amdgcn_mfma_f32_16x16x32_bf16(fah[i], fbl[j],
                                                            acc[i][j], 0, 0, 0);
#pragma unroll
    for (int i = 0; i < 4; ++i)
#pragma unroll
      for (int j = 0; j < 4; ++j)
        acc[i][j] = __builtin_amdgcn_mfma_f32_16x16x32_bf16(fal[i], fbh[j],
                                                            acc[i][j], 0, 0, 0);
  }

#pragma unroll
  for (int ti = 0; ti < 4; ++ti) {
#pragma unroll
    for (int r = 0; r < 4; ++r) {
      const int m = m0 + wm + ti * 16 + fq * 4 + r;
      if (m < N_NODES) {
#pragma unroll
        for (int tj = 0; tj < 4; ++tj) {
          const int n = n0 + wn + tj * 16 + fm;
          C[(size_t)m * FILTERS + n] = (_Float16)acc[ti][tj][r];
        }
      }
    }
  }
}

// ---------------------------------------------------------------------------
// CSR build
// ---------------------------------------------------------------------------
__global__ __launch_bounds__(256) void hist_kernel(const int* __restrict__ edst,
                                                   int* __restrict__ deg) {
  const int e = blockIdx.x * 256 + threadIdx.x;
  if (e < N_EDGES) atomicAdd(&deg[edst[e]], 1);
}

#define SCAN_NB 196
__global__ __launch_bounds__(256) void scan_blocks_kernel(
    const int* __restrict__ deg, int* __restrict__ row_ptr,
    int* __restrict__ bsum) {
  __shared__ int s[256];
  const int i = blockIdx.x * 256 + threadIdx.x;
  const int v = (i < N_NODES) ? deg[i] : 0;
  s[threadIdx.x] = v;
  __syncthreads();
  for (int off = 1; off < 256; off <<= 1) {
    const int t = (threadIdx.x >= off) ? s[threadIdx.x - off] : 0;
    __syncthreads();
    s[threadIdx.x] += t;
    __syncthreads();
  }
  if (i < N_NODES) row_ptr[i] = s[threadIdx.x] - v;
  if (threadIdx.x == 255) bsum[blockIdx.x] = s[255];
}

__global__ __launch_bounds__(256) void scan_sums_kernel(int* __restrict__ bsum) {
  __shared__ int s[256];
  const int v = (threadIdx.x < SCAN_NB) ? bsum[threadIdx.x] : 0;
  s[threadIdx.x] = v;
  __syncthreads();
  for (int off = 1; off < 256; off <<= 1) {
    const int t = (threadIdx.x >= off) ? s[threadIdx.x - off] : 0;
    __syncthreads();
    s[threadIdx.x] += t;
    __syncthreads();
  }
  if (threadIdx.x < SCAN_NB) bsum[threadIdx.x] = s[threadIdx.x] - v;
}

__global__ __launch_bounds__(256) void scan_add_kernel(
    int* __restrict__ row_ptr, const int* __restrict__ bsum,
    int* __restrict__ cursor) {
  const int i = blockIdx.x * 256 + threadIdx.x;
  if (i < N_NODES) {
    const int r = row_ptr[i] + bsum[blockIdx.x];
    row_ptr[i] = r;
    cursor[i] = r;
  }
  if (i == 0) row_ptr[N_NODES] = N_EDGES;
}

__global__ __launch_bounds__(256) void fill_kernel(
    const int* __restrict__ esrc, const int* __restrict__ edst,
    const float* __restrict__ ew, int* __restrict__ cursor,
    int2* __restrict__ meta) {
  const int e = blockIdx.x * 256 + threadIdx.x;
  if (e >= N_EDGES) return;
  const int d = edst[e];
  const int pos = atomicAdd(&cursor[d], 1);
  meta[pos] = make_int2(esrc[e], __float_as_int(ew[e]));
}

// ---------------------------------------------------------------------------
// Fused gather1 + relu + gemm2, edge-parallel two-phase.
// Block owns 8 dsts. Chunk of 128 edges: phase1 stages w*xw1[src] (fp16)
// into LDS edge-parallel (independent loads -> high MLP); phase2 segmented
// per-dst sum from LDS; epilogue = relu + W2 + butterfly + transpose.
// ---------------------------------------------------------------------------
#define G1_DPB 8
#define G1_CH 128
__global__ __launch_bounds__(256) void gather1_gemm2_kernel(
    const _Float16* __restrict__ xw1, const int* __restrict__ row_ptr,
    const int2* __restrict__ meta, const float* __restrict__ W2,
    float* __restrict__ h2) {
  __shared__ _Float16 stage[G1_CH * FILTERS];  // 64 KB
  __shared__ float red[4][16][17];
  const int wave = threadIdx.x >> 6;
  const int lane = threadIdx.x & 63;
  const int half = lane >> 5;
  const int fl = lane & 31;  // 16B feature chunk: feats [8*fl, 8*fl+8)
  const int n0 = blockIdx.x * G1_DPB;
  const int beg = row_ptr[n0];
  const int end = row_ptr[n0 + G1_DPB];

  // this wave's two dsts
  const int d0 = n0 + wave * 2;
  const int rp0 = row_ptr[d0];
  const int rp1 = row_ptr[d0 + 1];
  const int rp2 = row_ptr[d0 + 2];

  float acc[2][8] = {};

  for (int base = beg; base < end; base += G1_CH) {
    const int cend = min(base + G1_CH, end);

    // phase 1: this wave stages edges [base+wave*32, +32), 2 per step
    const int e0 = base + wave * 32;
#pragma unroll 2
    for (int j = 0; j < 16; ++j) {
      const int e = e0 + 2 * j + half;
      if (e < cend) {
        const int2 m = meta[e];
        const half8 v = ((const half8*)(xw1 + (size_t)m.x * FILTERS))[fl];
        const _Float16 wh = (_Float16)__int_as_float(m.y);
        half8 vw;
#pragma unroll
        for (int i = 0; i < 8; ++i) vw[i] = v[i] * wh;
        *(half8*)(stage + (size_t)(e - base) * FILTERS + fl * 8) = vw;
      }
    }
    __syncthreads();

    // phase 2: segmented sum for my 2 dsts (each half owns alternate edges)
#pragma unroll
    for (int s = 0; s < 2; ++s) {
      const int lb = max(s ? rp1 : rp0, base);
      const int le = min(s ? rp2 : rp1, cend);
      for (int e = lb + half; e < le; e += 2) {
        const half8 v =
            *(const half8*)(stage + (size_t)(e - base) * FILTERS + fl * 8);
#pragma unroll
        for (int i = 0; i < 8; ++i) acc[s][i] += (float)v[i];
      }
    }
    __syncthreads();
  }

  // epilogue per dst: merge halves, relu, W2, reduce, write
#pragma unroll
  for (int s = 0; s < 2; ++s) {
    float r[8];
#pragma unroll
    for (int i = 0; i < 8; ++i) {
      const float a = acc[s][i] + __shfl_xor(acc[s][i], 32, 64);
      r[i] = fmaxf(a, 0.f);
    }
    float p[16] = {};
#pragma unroll
    for (int i = 0; i < 8; ++i) {
      const float4* wr =
          (const float4*)(W2 + (size_t)(fl * 8 + i) * NUM_CLASSES);
#pragma unroll
      for (int c4 = 0; c4 < 4; ++c4) {
        const float4 wv = wr[c4];
        p[c4 * 4 + 0] = fmaf(r[i], wv.x, p[c4 * 4 + 0]);
        p[c4 * 4 + 1] = fmaf(r[i], wv.y, p[c4 * 4 + 1]);
        p[c4 * 4 + 2] = fmaf(r[i], wv.z, p[c4 * 4 + 2]);
        p[c4 * 4 + 3] = fmaf(r[i], wv.w, p[c4 * 4 + 3]);
      }
    }
#pragma unroll
    for (int off = 32; off >= 16; off >>= 1)
#pragma unroll
      for (int i = 0; i < 16; ++i) p[i] += __shfl_xor(p[i], off, 64);

    if (lane < 16) {
#pragma unroll
      for (int i = 0; i < 16; ++i) red[wave][lane][i] = p[i];
    }
    if (lane < 16) {
      float sum = 0.f;
#pragma unroll
      for (int i = 0; i < 16; ++i) sum += red[wave][i][lane];
      h2[(size_t)(d0 + s) * NUM_CLASSES + lane] = 0.5f * sum;
    }
  }
}

// ---------------------------------------------------------------------------
// Gather2 + softmax, edge-parallel two-phase. Block owns 32 dsts; chunk of
// 256 edges staged as w*h2row (fp32) in LDS; phase2 segmented sum + softmax.
// ---------------------------------------------------------------------------
#define G2_DPB 32
#define G2_CH 256
__global__ __launch_bounds__(256) void gather2_softmax_kernel(
    const float* __restrict__ h2, const int* __restrict__ row_ptr,
    const int2* __restrict__ meta, float* __restrict__ out) {
  __shared__ float st[G2_CH * NUM_CLASSES];  // 16 KB
  const int wave = threadIdx.x >> 6;
  const int lane = threadIdx.x & 63;
  const int q = lane >> 4;  // edge slot within step
  const int c = lane & 15;  // class
  const int n0 = blockIdx.x * G2_DPB;
  const int beg = row_ptr[min(n0, N_NODES)];
  const int end = row_ptr[min(n0 + G2_DPB, N_NODES)];

  // per-dst bounds for this wave's 8 dsts
  int rp[9];
#pragma unroll
  for (int s = 0; s <= 8; ++s)
    rp[s] = row_ptr[min(n0 + wave * 8 + s, N_NODES)];

  float acc[8] = {};

  for (int base = beg; base < end; base += G2_CH) {
    const int cend = min(base + G2_CH, end);
    const int e0 = base + wave * 64;
#pragma unroll 2
    for (int j = 0; j < 16; ++j) {
      const int e = e0 + 4 * j + q;
      if (e < cend) {
        const int2 m = meta[e];
        st[(e - base) * NUM_CLASSES + c] =
            __int_as_float(m.y) * h2[(size_t)m.x * NUM_CLASSES + c];
      }
    }
    __syncthreads();

#pragma unroll
    for (int s = 0; s < 8; ++s) {
      const int lb = max(rp[s], base);
      const int le = min(rp[s + 1], cend);
      for (int e = lb + q; e < le; e += 4)
        acc[s] += st[(e - base) * NUM_CLASSES + c];
    }
    __syncthreads();
  }

#pragma unroll
  for (int s = 0; s < 8; ++s) {
    float a = acc[s];
    a += __shfl_xor(a, 32, 64);
    a += __shfl_xor(a, 16, 64);
    float mx = a;
#pragma unroll
    for (int off = 8; off >= 1; off >>= 1)
      mx = fmaxf(mx, __shfl_xor(mx, off, 16));
    const float ex = __expf(a - mx);
    float sm = ex;
#pragma unroll
    for (int off = 8; off >= 1; off >>= 1) sm += __shfl_xor(sm, off, 16);
    const int d = n0 + wave * 8 + s;
    if (lane < 16 && d < N_NODES)
      out[(size_t)d * NUM_CLASSES + c] = ex / sm;
  }
}

extern "C" void kernel_launch(void* const* d_in, const int* in_sizes, int n_in,
                              void* d_out, int out_size, void* d_ws,
                              size_t ws_size, hipStream_t stream) {
  const float* x = (const float*)d_in[0];
  const float* W1 = (const float*)d_in[1];
  const float* W2 = (const float*)d_in[2];
  const float* ew = (const float*)d_in[3];
  const int* esrc = (const int*)d_in[4];
  const int* edst = (const int*)d_in[5];
  float* out = (float*)d_out;

  _Float16* xw1 = (_Float16*)d_ws;
  float* h2 = (float*)(xw1 + (size_t)N_NODES * FILTERS);
  int* row_ptr = (int*)(h2 + (size_t)N_NODES * NUM_CLASSES);
  int* cursor = row_ptr + (N_NODES + 1);
  int* deg = cursor + N_NODES;
  int2* meta = (int2*)(((uintptr_t)(deg + N_NODES) + 15) & ~(uintptr_t)15);
  __bf16* w1th = (__bf16*)(meta + N_EDGES);
  __bf16* w1tl = w1th + D_FEAT * FILTERS;
  int* bsum = (int*)(w1tl + D_FEAT * FILTERS);

  hipMemsetAsync(deg, 0, N_NODES * sizeof(int), stream);
  hist_kernel<<<(N_EDGES + 255) / 256, 256, 0, stream>>>(edst, deg);
  scan_blocks_kernel<<<SCAN_NB, 256, 0, stream>>>(deg, row_ptr, bsum);
  scan_sums_kernel<<<1, 256, 0, stream>>>(bsum);
  scan_add_kernel<<<SCAN_NB, 256, 0, stream>>>(row_ptr, bsum, cursor);
  fill_kernel<<<(N_EDGES + 255) / 256, 256, 0, stream>>>(esrc, edst, ew,
                                                         cursor, meta);

  split_w1_kernel<<<(D_FEAT * FILTERS) / 256, 256, 0, stream>>>(W1, w1th, w1tl);
  dim3 g1((N_NODES + 127) / 128, FILTERS / 128);
  gemm1_mfma_kernel<<<g1, 256, 0, stream>>>(x, w1th, w1tl, xw1);

  gather1_gemm2_kernel<<<N_NODES / G1_DPB, 256, 0, stream>>>(xw1, row_ptr,
                                                             meta, W2, h2);

  gather2_softmax_kernel<<<(N_NODES + G2_DPB - 1) / G2_DPB, 256, 0, stream>>>(
      h2, row_ptr, meta, out);
}

// Round 7
// 785.972 us; speedup vs baseline: 1.2152x; 1.2152x over previous
//
#include <hip/hip_runtime.h>

#define N_NODES 50000
#define N_EDGES 1600000
#define D_FEAT 512
#define FILTERS 256
#define NUM_CLASSES 16

typedef __bf16 bf16x8 __attribute__((ext_vector_type(8)));
typedef float f32x4 __attribute__((ext_vector_type(4)));
typedef _Float16 half8 __attribute__((ext_vector_type(8)));

#define GLOAD_LDS16(g, l)                                                  \
  __builtin_amdgcn_global_load_lds(                                        \
      (const __attribute__((address_space(1))) unsigned int*)(g),          \
      (__attribute__((address_space(3))) unsigned int*)(l), 16, 0, 0)

// ---------------------------------------------------------------------------
// Split W1 [512,256] fp32 -> W1^T hi/lo bf16 [256,512]
// ---------------------------------------------------------------------------
__global__ __launch_bounds__(256) void split_w1_kernel(
    const float* __restrict__ W1, __bf16* __restrict__ Wth,
    __bf16* __restrict__ Wtl) {
  const int idx = blockIdx.x * 256 + threadIdx.x;
  const int k = idx >> 8;
  const int n = idx & 255;
  const float v = W1[idx];
  const __bf16 h = (__bf16)v;
  const __bf16 l = (__bf16)(v - (float)h);
  Wth[n * D_FEAT + k] = h;
  Wtl[n * D_FEAT + k] = l;
}

// ---------------------------------------------------------------------------
// GEMM1 via MFMA bf16x3: XW1 = X @ W1, fp32-accurate, output stored fp16.
// ---------------------------------------------------------------------------
__global__ __launch_bounds__(256) void gemm1_mfma_kernel(
    const float* __restrict__ A, const __bf16* __restrict__ Bh,
    const __bf16* __restrict__ Bl, _Float16* __restrict__ C) {
  const int K = D_FEAT;
  __shared__ __bf16 sAh[128 * 32];
  __shared__ __bf16 sAl[128 * 32];
  __shared__ __bf16 sBh[128 * 32];
  __shared__ __bf16 sBl[128 * 32];

  const int tid = threadIdx.x;
  const int wave = tid >> 6;
  const int lane = tid & 63;
  const int wm = (wave >> 1) * 64;
  const int wn = (wave & 1) * 64;
  const int m0 = blockIdx.x * 128;
  const int n0 = blockIdx.y * 128;

  const int arow = tid >> 1;
  const int aks = (tid & 1) * 16;
  int am = m0 + arow;
  if (am >= N_NODES) am = N_NODES - 1;
  const float* aptr = A + (size_t)am * K + aks;

  const int lr = lane >> 2;
  const int lc = (lane & 3) * 8;
  const int fm = lane & 15;
  const int fq = lane >> 4;

  f32x4 acc[4][4] = {};

  for (int k0 = 0; k0 < K; k0 += 32) {
    const float4* ap = (const float4*)(aptr + k0);
    const float4 a0 = ap[0], a1 = ap[1], a2 = ap[2], a3 = ap[3];

    __syncthreads();

#pragma unroll
    for (int i = 0; i < 2; ++i) {
      const int row = wave * 32 + i * 16;
      GLOAD_LDS16(Bh + (size_t)(n0 + row + lr) * K + k0 + lc, sBh + row * 32);
      GLOAD_LDS16(Bl + (size_t)(n0 + row + lr) * K + k0 + lc, sBl + row * 32);
    }

    float va[16] = {a0.x, a0.y, a0.z, a0.w, a1.x, a1.y, a1.z, a1.w,
                    a2.x, a2.y, a2.z, a2.w, a3.x, a3.y, a3.z, a3.w};
    __bf16 hh[16], ll[16];
#pragma unroll
    for (int i = 0; i < 16; ++i) {
      const __bf16 h = (__bf16)va[i];
      hh[i] = h;
      ll[i] = (__bf16)(va[i] - (float)h);
    }
    *(bf16x8*)(sAh + arow * 32 + aks) = *(bf16x8*)&hh[0];
    *(bf16x8*)(sAh + arow * 32 + aks + 8) = *(bf16x8*)&hh[8];
    *(bf16x8*)(sAl + arow * 32 + aks) = *(bf16x8*)&ll[0];
    *(bf16x8*)(sAl + arow * 32 + aks + 8) = *(bf16x8*)&ll[8];

    __syncthreads();

    bf16x8 fah[4], fal[4], fbh[4], fbl[4];
#pragma unroll
    for (int t = 0; t < 4; ++t) {
      const int moff = (wm + t * 16 + fm) * 32 + fq * 8;
      fah[t] = *(const bf16x8*)(sAh + moff);
      fal[t] = *(const bf16x8*)(sAl + moff);
      const int noff = (wn + t * 16 + fm) * 32 + fq * 8;
      fbh[t] = *(const bf16x8*)(sBh + noff);
      fbl[t] = *(const bf16x8*)(sBl + noff);
    }
#pragma unroll
    for (int i = 0; i < 4; ++i)
#pragma unroll
      for (int j = 0; j < 4; ++j)
        acc[i][j] = __builtin_amdgcn_mfma_f32_16x16x32_bf16(fah[i], fbh[j],
                                                            acc[i][j], 0, 0, 0);
#pragma unroll
    for (int i = 0; i < 4; ++i)
#pragma unroll
      for (int j = 0; j < 4; ++j)
        acc[i][j] = __builtin_amdgcn_mfma_f32_16x16x32_bf16(fah[i], fbl[j],
                                                            acc[i][j], 0, 0, 0);
#pragma unroll
    for (int i = 0; i < 4; ++i)
#pragma unroll
      for (int j = 0; j < 4; ++j)
        acc[i][j] = __builtin_amdgcn_mfma_f32_16x16x32_bf16(fal[i], fbh[j],
                                                            acc[i][j], 0, 0, 0);
  }

#pragma unroll
  for (int ti = 0; ti < 4; ++ti) {
#pragma unroll
    for (int r = 0; r < 4; ++r) {
      const int m = m0 + wm + ti * 16 + fq * 4 + r;
      if (m < N_NODES) {
#pragma unroll
        for (int tj = 0; tj < 4; ++tj) {
          const int n = n0 + wn + tj * 16 + fm;
          C[(size_t)m * FILTERS + n] = (_Float16)acc[ti][tj][r];
        }
      }
    }
  }
}

// ---------------------------------------------------------------------------
// CSR build
// ---------------------------------------------------------------------------
__global__ __launch_bounds__(256) void hist_kernel(const int* __restrict__ edst,
                                                   int* __restrict__ deg) {
  const int e = blockIdx.x * 256 + threadIdx.x;
  if (e < N_EDGES) atomicAdd(&deg[edst[e]], 1);
}

#define SCAN_NB 196
__global__ __launch_bounds__(256) void scan_blocks_kernel(
    const int* __restrict__ deg, int* __restrict__ row_ptr,
    int* __restrict__ bsum) {
  __shared__ int s[256];
  const int i = blockIdx.x * 256 + threadIdx.x;
  const int v = (i < N_NODES) ? deg[i] : 0;
  s[threadIdx.x] = v;
  __syncthreads();
  for (int off = 1; off < 256; off <<= 1) {
    const int t = (threadIdx.x >= off) ? s[threadIdx.x - off] : 0;
    __syncthreads();
    s[threadIdx.x] += t;
    __syncthreads();
  }
  if (i < N_NODES) row_ptr[i] = s[threadIdx.x] - v;
  if (threadIdx.x == 255) bsum[blockIdx.x] = s[255];
}

__global__ __launch_bounds__(256) void scan_sums_kernel(int* __restrict__ bsum) {
  __shared__ int s[256];
  const int v = (threadIdx.x < SCAN_NB) ? bsum[threadIdx.x] : 0;
  s[threadIdx.x] = v;
  __syncthreads();
  for (int off = 1; off < 256; off <<= 1) {
    const int t = (threadIdx.x >= off) ? s[threadIdx.x - off] : 0;
    __syncthreads();
    s[threadIdx.x] += t;
    __syncthreads();
  }
  if (threadIdx.x < SCAN_NB) bsum[threadIdx.x] = s[threadIdx.x] - v;
}

__global__ __launch_bounds__(256) void scan_add_kernel(
    int* __restrict__ row_ptr, const int* __restrict__ bsum,
    int* __restrict__ cursor) {
  const int i = blockIdx.x * 256 + threadIdx.x;
  if (i < N_NODES) {
    const int r = row_ptr[i] + bsum[blockIdx.x];
    row_ptr[i] = r;
    cursor[i] = r;
  }
  if (i == 0) row_ptr[N_NODES] = N_EDGES;
}

// Fill: dst-sorted meta = (src, w_bits, dst, 0)
__global__ __launch_bounds__(256) void fill_kernel(
    const int* __restrict__ esrc, const int* __restrict__ edst,
    const float* __restrict__ ew, int* __restrict__ cursor,
    int4* __restrict__ meta) {
  const int e = blockIdx.x * 256 + threadIdx.x;
  if (e >= N_EDGES) return;
  const int d = edst[e];
  const int pos = atomicAdd(&cursor[d], 1);
  meta[pos] = make_int4(esrc[e], __float_as_int(ew[e]), d, 0);
}

// ---------------------------------------------------------------------------
// Gather1 + relu + gemm2. Block owns 32 dsts. Two 32-lane halves each walk
// half of the block's edge range (different dsts), so ONE wave instruction
// loads TWO edges' 512B rows (0.5 row-instr/edge). Accumulate per-dst in
// LDS fp32 tile (stride 257 -> 32 banks) with register run-combining
// (flush via ds_add atomics only when dst changes).
// ---------------------------------------------------------------------------
#define G1_DPB 32
__global__ __launch_bounds__(256) void gather1_gemm2_kernel(
    const _Float16* __restrict__ xw1, const int* __restrict__ row_ptr,
    const int4* __restrict__ meta, const float* __restrict__ W2,
    float* __restrict__ h2) {
  __shared__ float acc[32 * 257];  // [chunk fl][dst*8 + i], 32.9 KB
  __shared__ float red[4][16][17];
  const int tid = threadIdx.x;
  const int wave = tid >> 6;
  const int lane = tid & 63;
  const int half = lane >> 5;
  const int fl = lane & 31;  // feature chunk: feats [8*fl, 8*fl+8)
  const int n0 = blockIdx.x * G1_DPB;
  const int nend = min(n0 + G1_DPB, N_NODES);
  const int beg = row_ptr[n0];
  const int end = row_ptr[nend];
  const int nE = end - beg;
  const int mid = nE >> 1;

  for (int i = tid; i < 32 * 257; i += 256) acc[i] = 0.f;
  __syncthreads();

  // my region: half 0 -> [0, mid), half 1 -> [mid, nE)
  const int rbase = beg + (half ? mid : 0);
  const int rcnt = half ? (nE - mid) : mid;

  float racc[8] = {};
  int cur = -1;  // current local dst being register-accumulated
  float* arow = acc + fl * 257;

  for (int j = wave; j < rcnt; j += 4) {
    const int4 m = meta[rbase + j];
    const float w = __int_as_float(m.y);
    const half8 v = *(const half8*)(xw1 + (size_t)m.x * FILTERS + fl * 8);
    const int ld = m.z - n0;
    if (ld != cur) {
      if (cur >= 0) {
#pragma unroll
        for (int i = 0; i < 8; ++i) atomicAdd(arow + cur * 8 + i, racc[i]);
      }
#pragma unroll
      for (int i = 0; i < 8; ++i) racc[i] = 0.f;
      cur = ld;
    }
#pragma unroll
    for (int i = 0; i < 8; ++i) racc[i] = fmaf(w, (float)v[i], racc[i]);
  }
  if (cur >= 0) {
#pragma unroll
    for (int i = 0; i < 8; ++i) atomicAdd(arow + cur * 8 + i, racc[i]);
  }
  __syncthreads();

  // epilogue: wave handles dsts n0+wave, n0+wave+4, ...
  for (int d = n0 + wave; d < nend; d += 4) {
    const int ld = d - n0;
    // lane owns feats lane*4 .. +3 -> chunk lane>>1, idx 4*(lane&1)+j
    float r[4];
#pragma unroll
    for (int j = 0; j < 4; ++j) {
      const float a = acc[(lane >> 1) * 257 + ld * 8 + 4 * (lane & 1) + j];
      r[j] = fmaxf(a, 0.f);
    }
    float p[16] = {};
#pragma unroll
    for (int j = 0; j < 4; ++j) {
      const float4* wr =
          (const float4*)(W2 + (size_t)(lane * 4 + j) * NUM_CLASSES);
#pragma unroll
      for (int c4 = 0; c4 < 4; ++c4) {
        const float4 wv = wr[c4];
        p[c4 * 4 + 0] = fmaf(r[j], wv.x, p[c4 * 4 + 0]);
        p[c4 * 4 + 1] = fmaf(r[j], wv.y, p[c4 * 4 + 1]);
        p[c4 * 4 + 2] = fmaf(r[j], wv.z, p[c4 * 4 + 2]);
        p[c4 * 4 + 3] = fmaf(r[j], wv.w, p[c4 * 4 + 3]);
      }
    }
#pragma unroll
    for (int off = 32; off >= 16; off >>= 1)
#pragma unroll
      for (int i = 0; i < 16; ++i) p[i] += __shfl_xor(p[i], off, 64);

    if (lane < 16) {
#pragma unroll
      for (int i = 0; i < 16; ++i) red[wave][lane][i] = p[i];
    }
    if (lane < 16) {
      float sum = 0.f;
#pragma unroll
      for (int i = 0; i < 16; ++i) sum += red[wave][i][lane];
      h2[(size_t)d * NUM_CLASSES + lane] = sum;
    }
  }
}

// ---------------------------------------------------------------------------
// Gather2 + softmax. Block owns 64 dsts. 64 groups of 4 lanes; group g walks
// its own contiguous CHUNK of the block's edge range (16 edges loaded per
// wave instruction, groups target different dsts). Register run-combining,
// LDS fp32 tile [64][17], fused softmax.
// ---------------------------------------------------------------------------
#define G2_DPB 64
__global__ __launch_bounds__(256) void gather2_softmax_kernel(
    const float* __restrict__ h2, const int* __restrict__ row_ptr,
    const int4* __restrict__ meta, float* __restrict__ out) {
  __shared__ float acc[G2_DPB * 17];  // 4.4 KB
  const int tid = threadIdx.x;
  const int wave = tid >> 6;
  const int lane = tid & 63;
  const int grp = tid >> 2;  // 0..63: edge chunk owner
  const int q = tid & 3;     // class quad: classes q*4..+3
  const int n0 = blockIdx.x * G2_DPB;
  const int nend = min(n0 + G2_DPB, N_NODES);
  const int beg = row_ptr[n0];
  const int end = row_ptr[nend];
  const int nE = end - beg;

  for (int i = tid; i < G2_DPB * 17; i += 256) acc[i] = 0.f;
  __syncthreads();

  const int cs = (nE + 63) >> 6;  // chunk size
  const int cb = grp * cs;
  const int ce = min(cb + cs, nE);

  float racc[4] = {};
  int cur = -1;
  for (int j = cb; j < ce; ++j) {
    const int4 m = meta[beg + j];
    const float w = __int_as_float(m.y);
    const float4 v = *(const float4*)(h2 + (size_t)m.x * NUM_CLASSES + q * 4);
    const int ld = m.z - n0;
    if (ld != cur) {
      if (cur >= 0) {
#pragma unroll
        for (int i = 0; i < 4; ++i)
          atomicAdd(&acc[cur * 17 + q * 4 + i], racc[i]);
      }
#pragma unroll
      for (int i = 0; i < 4; ++i) racc[i] = 0.f;
      cur = ld;
    }
    racc[0] = fmaf(w, v.x, racc[0]);
    racc[1] = fmaf(w, v.y, racc[1]);
    racc[2] = fmaf(w, v.z, racc[2]);
    racc[3] = fmaf(w, v.w, racc[3]);
  }
  if (cur >= 0) {
#pragma unroll
    for (int i = 0; i < 4; ++i) atomicAdd(&acc[cur * 17 + q * 4 + i], racc[i]);
  }
  __syncthreads();

  // softmax: wave covers 16 dsts in 4 passes of 4; lane = (d4 = lane>>4, c)
  const int d4 = lane >> 4;
  const int c = lane & 15;
#pragma unroll
  for (int pass = 0; pass < 4; ++pass) {
    const int d = n0 + wave * 16 + pass * 4 + d4;
    const int ld = wave * 16 + pass * 4 + d4;
    float a = (d < N_NODES) ? acc[ld * 17 + c] : 0.f;
    float mx = a;
#pragma unroll
    for (int off = 8; off >= 1; off >>= 1)
      mx = fmaxf(mx, __shfl_xor(mx, off, 16));
    const float ex = __expf(a - mx);
    float sm = ex;
#pragma unroll
    for (int off = 8; off >= 1; off >>= 1) sm += __shfl_xor(sm, off, 16);
    if (d < N_NODES) out[(size_t)d * NUM_CLASSES + c] = ex / sm;
  }
}

extern "C" void kernel_launch(void* const* d_in, const int* in_sizes, int n_in,
                              void* d_out, int out_size, void* d_ws,
                              size_t ws_size, hipStream_t stream) {
  const float* x = (const float*)d_in[0];
  const float* W1 = (const float*)d_in[1];
  const float* W2 = (const float*)d_in[2];
  const float* ew = (const float*)d_in[3];
  const int* esrc = (const int*)d_in[4];
  const int* edst = (const int*)d_in[5];
  float* out = (float*)d_out;

  _Float16* xw1 = (_Float16*)d_ws;                            // 25.6 MB
  float* h2 = (float*)(xw1 + (size_t)N_NODES * FILTERS);      // 3.2 MB
  int* row_ptr = (int*)(h2 + (size_t)N_NODES * NUM_CLASSES);  // 50001
  int* cursor = row_ptr + (N_NODES + 1);
  int* deg = cursor + N_NODES;
  int4* meta = (int4*)(((uintptr_t)(deg + N_NODES) + 15) & ~(uintptr_t)15);
  __bf16* w1th = (__bf16*)(meta + N_EDGES);  // 25.6 MB meta
  __bf16* w1tl = w1th + D_FEAT * FILTERS;
  int* bsum = (int*)(w1tl + D_FEAT * FILTERS);

  hipMemsetAsync(deg, 0, N_NODES * sizeof(int), stream);
  hist_kernel<<<(N_EDGES + 255) / 256, 256, 0, stream>>>(edst, deg);
  scan_blocks_kernel<<<SCAN_NB, 256, 0, stream>>>(deg, row_ptr, bsum);
  scan_sums_kernel<<<1, 256, 0, stream>>>(bsum);
  scan_add_kernel<<<SCAN_NB, 256, 0, stream>>>(row_ptr, bsum, cursor);
  fill_kernel<<<(N_EDGES + 255) / 256, 256, 0, stream>>>(esrc, edst, ew,
                                                         cursor, meta);

  split_w1_kernel<<<(D_FEAT * FILTERS) / 256, 256, 0, stream>>>(W1, w1th, w1tl);
  dim3 g1((N_NODES + 127) / 128, FILTERS / 128);
  gemm1_mfma_kernel<<<g1, 256, 0, stream>>>(x, w1th, w1tl, xw1);

  gather1_gemm2_kernel<<<(N_NODES + G1_DPB - 1) / G1_DPB, 256, 0, stream>>>(
      xw1, row_ptr, meta, W2, h2);

  gather2_softmax_kernel<<<(N_NODES + G2_DPB - 1) / G2_DPB, 256, 0, stream>>>(
      h2, row_ptr, meta, out);
}

// Round 8
// 640.389 us; speedup vs baseline: 1.4914x; 1.2273x over previous
//
#include <hip/hip_runtime.h>

#define N_NODES 50000
#define N_EDGES 1600000
#define D_FEAT 512
#define FILTERS 256
#define NUM_CLASSES 16

typedef __bf16 bf16x8 __attribute__((ext_vector_type(8)));
typedef float f32x4 __attribute__((ext_vector_type(4)));
typedef _Float16 half4 __attribute__((ext_vector_type(4)));
typedef _Float16 f16x8 __attribute__((ext_vector_type(8)));

#define GLOAD_LDS16(g, l)                                                  \
  __builtin_amdgcn_global_load_lds(                                        \
      (const __attribute__((address_space(1))) unsigned int*)(g),          \
      (__attribute__((address_space(3))) unsigned int*)(l), 16, 0, 0)

// ---------------------------------------------------------------------------
// Split W1 [512,256] fp32 -> W1^T hi/lo bf16 [256,512]
// ---------------------------------------------------------------------------
__global__ __launch_bounds__(256) void split_w1_kernel(
    const float* __restrict__ W1, __bf16* __restrict__ Wth,
    __bf16* __restrict__ Wtl) {
  const int idx = blockIdx.x * 256 + threadIdx.x;
  const int k = idx >> 8;
  const int n = idx & 255;
  const float v = W1[idx];
  const __bf16 h = (__bf16)v;
  const __bf16 l = (__bf16)(v - (float)h);
  Wth[n * D_FEAT + k] = h;
  Wtl[n * D_FEAT + k] = l;
}

// ---------------------------------------------------------------------------
// GEMM1 via MFMA bf16x3: XW1 = X @ W1, fp32-accurate, output stored fp16.
// ---------------------------------------------------------------------------
__global__ __launch_bounds__(256) void gemm1_mfma_kernel(
    const float* __restrict__ A, const __bf16* __restrict__ Bh,
    const __bf16* __restrict__ Bl, _Float16* __restrict__ C) {
  const int K = D_FEAT;
  __shared__ __bf16 sAh[128 * 32];
  __shared__ __bf16 sAl[128 * 32];
  __shared__ __bf16 sBh[128 * 32];
  __shared__ __bf16 sBl[128 * 32];

  const int tid = threadIdx.x;
  const int wave = tid >> 6;
  const int lane = tid & 63;
  const int wm = (wave >> 1) * 64;
  const int wn = (wave & 1) * 64;
  const int m0 = blockIdx.x * 128;
  const int n0 = blockIdx.y * 128;

  const int arow = tid >> 1;
  const int aks = (tid & 1) * 16;
  int am = m0 + arow;
  if (am >= N_NODES) am = N_NODES - 1;
  const float* aptr = A + (size_t)am * K + aks;

  const int lr = lane >> 2;
  const int lc = (lane & 3) * 8;
  const int fm = lane & 15;
  const int fq = lane >> 4;

  f32x4 acc[4][4] = {};

  for (int k0 = 0; k0 < K; k0 += 32) {
    const float4* ap = (const float4*)(aptr + k0);
    const float4 a0 = ap[0], a1 = ap[1], a2 = ap[2], a3 = ap[3];

    __syncthreads();

#pragma unroll
    for (int i = 0; i < 2; ++i) {
      const int row = wave * 32 + i * 16;
      GLOAD_LDS16(Bh + (size_t)(n0 + row + lr) * K + k0 + lc, sBh + row * 32);
      GLOAD_LDS16(Bl + (size_t)(n0 + row + lr) * K + k0 + lc, sBl + row * 32);
    }

    float va[16] = {a0.x, a0.y, a0.z, a0.w, a1.x, a1.y, a1.z, a1.w,
                    a2.x, a2.y, a2.z, a2.w, a3.x, a3.y, a3.z, a3.w};
    __bf16 hh[16], ll[16];
#pragma unroll
    for (int i = 0; i < 16; ++i) {
      const __bf16 h = (__bf16)va[i];
      hh[i] = h;
      ll[i] = (__bf16)(va[i] - (float)h);
    }
    *(bf16x8*)(sAh + arow * 32 + aks) = *(bf16x8*)&hh[0];
    *(bf16x8*)(sAh + arow * 32 + aks + 8) = *(bf16x8*)&hh[8];
    *(bf16x8*)(sAl + arow * 32 + aks) = *(bf16x8*)&ll[0];
    *(bf16x8*)(sAl + arow * 32 + aks + 8) = *(bf16x8*)&ll[8];

    __syncthreads();

    bf16x8 fah[4], fal[4], fbh[4], fbl[4];
#pragma unroll
    for (int t = 0; t < 4; ++t) {
      const int moff = (wm + t * 16 + fm) * 32 + fq * 8;
      fah[t] = *(const bf16x8*)(sAh + moff);
      fal[t] = *(const bf16x8*)(sAl + moff);
      const int noff = (wn + t * 16 + fm) * 32 + fq * 8;
      fbh[t] = *(const bf16x8*)(sBh + noff);
      fbl[t] = *(const bf16x8*)(sBl + noff);
    }
#pragma unroll
    for (int i = 0; i < 4; ++i)
#pragma unroll
      for (int j = 0; j < 4; ++j)
        acc[i][j] = __builtin_amdgcn_mfma_f32_16x16x32_bf16(fah[i], fbh[j],
                                                            acc[i][j], 0, 0, 0);
#pragma unroll
    for (int i = 0; i < 4; ++i)
#pragma unroll
      for (int j = 0; j < 4; ++j)
        acc[i][j] = __builtin_amdgcn_mfma_f32_16x16x32_bf16(fah[i], fbl[j],
                                                            acc[i][j], 0, 0, 0);
#pragma unroll
    for (int i = 0; i < 4; ++i)
#pragma unroll
      for (int j = 0; j < 4; ++j)
        acc[i][j] = __builtin_amdgcn_mfma_f32_16x16x32_bf16(fal[i], fbh[j],
                                                            acc[i][j], 0, 0, 0);
  }

#pragma unroll
  for (int ti = 0; ti < 4; ++ti) {
#pragma unroll
    for (int r = 0; r < 4; ++r) {
      const int m = m0 + wm + ti * 16 + fq * 4 + r;
      if (m < N_NODES) {
#pragma unroll
        for (int tj = 0; tj < 4; ++tj) {
          const int n = n0 + wn + tj * 16 + fm;
          C[(size_t)m * FILTERS + n] = (_Float16)acc[ti][tj][r];
        }
      }
    }
  }
}

// ---------------------------------------------------------------------------
// CSR build
// ---------------------------------------------------------------------------
__global__ __launch_bounds__(256) void hist_kernel(const int* __restrict__ edst,
                                                   int* __restrict__ deg) {
  const int e = blockIdx.x * 256 + threadIdx.x;
  if (e < N_EDGES) atomicAdd(&deg[edst[e]], 1);
}

#define SCAN_NB 196
__global__ __launch_bounds__(256) void scan_blocks_kernel(
    const int* __restrict__ deg, int* __restrict__ row_ptr,
    int* __restrict__ bsum) {
  __shared__ int s[256];
  const int i = blockIdx.x * 256 + threadIdx.x;
  const int v = (i < N_NODES) ? deg[i] : 0;
  s[threadIdx.x] = v;
  __syncthreads();
  for (int off = 1; off < 256; off <<= 1) {
    const int t = (threadIdx.x >= off) ? s[threadIdx.x - off] : 0;
    __syncthreads();
    s[threadIdx.x] += t;
    __syncthreads();
  }
  if (i < N_NODES) row_ptr[i] = s[threadIdx.x] - v;
  if (threadIdx.x == 255) bsum[blockIdx.x] = s[255];
}

__global__ __launch_bounds__(256) void scan_sums_kernel(int* __restrict__ bsum) {
  __shared__ int s[256];
  const int v = (threadIdx.x < SCAN_NB) ? bsum[threadIdx.x] : 0;
  s[threadIdx.x] = v;
  __syncthreads();
  for (int off = 1; off < 256; off <<= 1) {
    const int t = (threadIdx.x >= off) ? s[threadIdx.x - off] : 0;
    __syncthreads();
    s[threadIdx.x] += t;
    __syncthreads();
  }
  if (threadIdx.x < SCAN_NB) bsum[threadIdx.x] = s[threadIdx.x] - v;
}

__global__ __launch_bounds__(256) void scan_add_kernel(
    int* __restrict__ row_ptr, const int* __restrict__ bsum,
    int* __restrict__ cursor) {
  const int i = blockIdx.x * 256 + threadIdx.x;
  if (i < N_NODES) {
    const int r = row_ptr[i] + bsum[blockIdx.x];
    row_ptr[i] = r;
    cursor[i] = r;
  }
  if (i == 0) row_ptr[N_NODES] = N_EDGES;
}

// Fill: dst-sorted meta = (src, w_bits, dst, 0)
__global__ __launch_bounds__(256) void fill_kernel(
    const int* __restrict__ esrc, const int* __restrict__ edst,
    const float* __restrict__ ew, int* __restrict__ cursor,
    int4* __restrict__ meta) {
  const int e = blockIdx.x * 256 + threadIdx.x;
  if (e >= N_EDGES) return;
  const int d = edst[e];
  const int pos = atomicAdd(&cursor[d], 1);
  meta[pos] = make_int4(esrc[e], __float_as_int(ew[e]), d, 0);
}

// ---------------------------------------------------------------------------
// Fused gather1 + relu + gemm2 (r4 structure: one wave per node, serial
// edges, zero LDS in the hot loop — best measured variant). h2 out = fp16.
// ---------------------------------------------------------------------------
__global__ __launch_bounds__(256) void gather1_gemm2_kernel(
    const _Float16* __restrict__ xw1, const int* __restrict__ row_ptr,
    const int4* __restrict__ meta, const float* __restrict__ W2,
    _Float16* __restrict__ h2) {
  __shared__ float red[4][16][17];
  const int wave = threadIdx.x >> 6;
  const int lane = threadIdx.x & 63;
  const int node = blockIdx.x * 4 + wave;
  const int beg = row_ptr[node];
  const int end = row_ptr[node + 1];

  float acc[4] = {};
  for (int j = beg; j < end; ++j) {
    const int4 m = meta[j];
    const float w = __int_as_float(m.y);
    const half4 v = ((const half4*)(xw1 + (size_t)m.x * FILTERS))[lane];
#pragma unroll
    for (int i = 0; i < 4; ++i) acc[i] = fmaf(w, (float)v[i], acc[i]);
  }

  float r[4];
#pragma unroll
  for (int i = 0; i < 4; ++i) r[i] = fmaxf(acc[i], 0.f);

  // gemm2 partials: lane's k = lane*4 + j (covers all 256 k across 64 lanes)
  float p[16] = {};
#pragma unroll
  for (int j = 0; j < 4; ++j) {
    const float4* wr = (const float4*)(W2 + (size_t)(lane * 4 + j) * NUM_CLASSES);
#pragma unroll
    for (int c4 = 0; c4 < 4; ++c4) {
      const float4 wv = wr[c4];
      p[c4 * 4 + 0] = fmaf(r[j], wv.x, p[c4 * 4 + 0]);
      p[c4 * 4 + 1] = fmaf(r[j], wv.y, p[c4 * 4 + 1]);
      p[c4 * 4 + 2] = fmaf(r[j], wv.z, p[c4 * 4 + 2]);
      p[c4 * 4 + 3] = fmaf(r[j], wv.w, p[c4 * 4 + 3]);
    }
  }

#pragma unroll
  for (int off = 32; off >= 16; off >>= 1)
#pragma unroll
    for (int i = 0; i < 16; ++i) p[i] += __shfl_xor(p[i], off, 64);

  if (lane < 16) {
#pragma unroll
    for (int i = 0; i < 16; ++i) red[wave][lane][i] = p[i];
  }
  if (lane < 16) {
    float sum = 0.f;
#pragma unroll
    for (int i = 0; i < 16; ++i) sum += red[wave][i][lane];
    h2[(size_t)node * NUM_CLASSES + lane] = (_Float16)sum;
  }
}

// ---------------------------------------------------------------------------
// Gather2 + softmax via MFMA. One wave per 16-dst tile (50000 = 16*3125).
// Per 32-edge chunk: A = selection matrix Sel[dst][edge] (w_e where
// dst_e==dst) built in registers via shfl; B = h2 fp16 rows staged by ONE
// global b128 instruction (32 rows) and transposed into wave-private LDS
// [16 classes][40 edges]; one mfma_f32_16x16x32_f16. No __syncthreads.
// C layout: row = dst-local = (lane>>4)*4+reg, col = class = lane&15.
// ---------------------------------------------------------------------------
__global__ __launch_bounds__(256) void gather2_mfma_kernel(
    const _Float16* __restrict__ h2, const int* __restrict__ row_ptr,
    const int4* __restrict__ meta, float* __restrict__ out) {
  __shared__ _Float16 lds[4][16][40];  // per-wave 1.25 KB slice
  const int wave = threadIdx.x >> 6;
  const int lane = threadIdx.x & 63;
  const int tile = blockIdx.x * 4 + wave;
  if (tile >= N_NODES / 16) return;
  const int t0 = tile * 16;
  const int beg = row_ptr[t0];
  const int end = row_ptr[t0 + 16];

  const int cls = lane & 15;   // class (N) / dst-local for A (M)
  const int kq = lane >> 4;    // k-octet
  const int erow = lane >> 1;  // staged edge 0..31
  const int part = lane & 1;   // class half for staging

  f32x4 acc = {0.f, 0.f, 0.f, 0.f};
  _Float16* myl = &lds[wave][0][0];

  for (int c0 = beg; c0 < end; c0 += 32) {
    // meta for this chunk's 32 edges in lanes 0..31
    int4 m;
    m.x = 0; m.y = 0; m.z = t0; m.w = 0;
    if (lane < 32) {
      const int e = c0 + lane;
      if (e < end) m = meta[e];
    }

    // A-frag: Sel[m=dst-local][k=edge] = w_e * (dst_e == m)
    f16x8 afrag;
#pragma unroll
    for (int j = 0; j < 8; ++j) {
      const int ei = kq * 8 + j;
      const int de = __shfl(m.z, ei, 64) - t0;
      const float we = __int_as_float(__shfl(m.y, ei, 64));
      afrag[j] = (de == cls) ? (_Float16)we : (_Float16)0.f;
    }

    // stage 32 rows (one b128 per lane): lane = (edge erow, classes part*8..+8)
    const int se = __shfl(m.x, erow, 64);
    const f16x8 rv = *(const f16x8*)(h2 + (size_t)se * NUM_CLASSES + part * 8);
#pragma unroll
    for (int j = 0; j < 8; ++j) myl[(part * 8 + j) * 40 + erow] = rv[j];

    // B-frag: B[k=edge][n=class] from transposed LDS (contiguous b128)
    const f16x8 bfrag = *(const f16x8*)(myl + cls * 40 + kq * 8);

    acc = __builtin_amdgcn_mfma_f32_16x16x32_f16(afrag, bfrag, acc, 0, 0, 0);
  }

  // softmax per dst (classes live across the quad's 16 lanes)
#pragma unroll
  for (int r = 0; r < 4; ++r) {
    const float a = acc[r];
    float mx = a;
#pragma unroll
    for (int off = 8; off >= 1; off >>= 1)
      mx = fmaxf(mx, __shfl_xor(mx, off, 16));
    const float ex = __expf(a - mx);
    float sm = ex;
#pragma unroll
    for (int off = 8; off >= 1; off >>= 1) sm += __shfl_xor(sm, off, 16);
    out[(size_t)(t0 + kq * 4 + r) * NUM_CLASSES + cls] = ex / sm;
  }
}

extern "C" void kernel_launch(void* const* d_in, const int* in_sizes, int n_in,
                              void* d_out, int out_size, void* d_ws,
                              size_t ws_size, hipStream_t stream) {
  const float* x = (const float*)d_in[0];
  const float* W1 = (const float*)d_in[1];
  const float* W2 = (const float*)d_in[2];
  const float* ew = (const float*)d_in[3];
  const int* esrc = (const int*)d_in[4];
  const int* edst = (const int*)d_in[5];
  float* out = (float*)d_out;

  _Float16* xw1 = (_Float16*)d_ws;                               // 25.6 MB
  _Float16* h2 = xw1 + (size_t)N_NODES * FILTERS;                // 1.6 MB
  int* row_ptr = (int*)(h2 + (size_t)N_NODES * NUM_CLASSES);     // 50001
  int* cursor = row_ptr + (N_NODES + 1);
  int* deg = cursor + N_NODES;
  int4* meta = (int4*)(((uintptr_t)(deg + N_NODES) + 15) & ~(uintptr_t)15);
  __bf16* w1th = (__bf16*)(meta + N_EDGES);                      // 25.6 MB meta
  __bf16* w1tl = w1th + D_FEAT * FILTERS;
  int* bsum = (int*)(w1tl + D_FEAT * FILTERS);

  hipMemsetAsync(deg, 0, N_NODES * sizeof(int), stream);
  hist_kernel<<<(N_EDGES + 255) / 256, 256, 0, stream>>>(edst, deg);
  scan_blocks_kernel<<<SCAN_NB, 256, 0, stream>>>(deg, row_ptr, bsum);
  scan_sums_kernel<<<1, 256, 0, stream>>>(bsum);
  scan_add_kernel<<<SCAN_NB, 256, 0, stream>>>(row_ptr, bsum, cursor);
  fill_kernel<<<(N_EDGES + 255) / 256, 256, 0, stream>>>(esrc, edst, ew,
                                                         cursor, meta);

  split_w1_kernel<<<(D_FEAT * FILTERS) / 256, 256, 0, stream>>>(W1, w1th, w1tl);
  dim3 g1((N_NODES + 127) / 128, FILTERS / 128);
  gemm1_mfma_kernel<<<g1, 256, 0, stream>>>(x, w1th, w1tl, xw1);

  gather1_gemm2_kernel<<<N_NODES / 4, 256, 0, stream>>>(xw1, row_ptr, meta, W2,
                                                        h2);

  // 3125 tiles of 16 dsts, 4 per block
  gather2_mfma_kernel<<<(N_NODES / 16 + 3) / 4, 256, 0, stream>>>(h2, row_ptr,
                                                                  meta, out);
}